// Round 4
// baseline (401.079 us; speedup 1.0000x reference)
//
#include <hip/hip_runtime.h>
#include <math.h>

// Deformation4D: N=1M gaussians, K_NB=10, K_TOTAL=300 control points.
// R4 = R1 structure + compressed LDS record, NO software prefetch (R3's
// double-buffer arrays spilled to scratch: WRITE_SIZE 35->243 MB).
// LDS record per CP: 2 x float4 at stride 3 float4s (12 dwords -> cp*12 mod 32
// cycles through 8 bank-start groups): [qhat.wxyz], [|q|, bx, by, bz],
// b = p + t - rot(qhat, p). Per neighbor: 2 ds_read_b128 + ~30 VALU.
// dm   = sum_k w_k * (rot(qhat_k, m) + b_k)
// qacc = sum_k (w_k * |q|_k) * qhat_k     (== sum w_k * q_raw_k)
// Grid: 2048 blocks (8/CU: LDS 14.4KB x 8 = 115KB, 32 waves) x ~2 chunks.

__device__ __forceinline__ float3 quat_rotate(float qw, float qx, float qy, float qz,
                                              float vx, float vy, float vz) {
    // v' = v + qw*t + cross(qv, t),  t = 2*cross(qv, v)
    float cx = qy * vz - qz * vy;
    float cy = qz * vx - qx * vz;
    float cz = qx * vy - qy * vx;
    float tx = cx + cx, ty = cy + cy, tz = cz + cz;
    float rx = fmaf(qy, tz, fmaf(-qz, ty, fmaf(qw, tx, vx)));
    float ry = fmaf(qz, tx, fmaf(-qx, tz, fmaf(qw, ty, vy)));
    float rz = fmaf(qx, ty, fmaf(-qy, tx, fmaf(qw, tz, vz)));
    return make_float3(rx, ry, rz);
}

template <int KNB>
__global__ __launch_bounds__(256, 8) void deform_kernel(
    const float* __restrict__ means,
    const float* __restrict__ quats,
    const float* __restrict__ weights,
    const float* __restrict__ ctrl_trans,
    const float* __restrict__ ctrl_rot,
    const float* __restrict__ ctrl_pos,
    const int*   __restrict__ indices,
    float* __restrict__ out_means,
    float* __restrict__ out_quats,
    int N, int K_TOTAL)
{
    extern __shared__ float4 sT[];   // sT[cp*3+0]=qhat(wxyz), sT[cp*3+1]=(|q|,bx,by,bz)

    // ---- build compressed control-point table ----
    for (int cp = threadIdx.x; cp < K_TOTAL; cp += blockDim.x) {
        float4 q = ((const float4*)ctrl_rot)[cp];
        float n   = sqrtf(q.x*q.x + q.y*q.y + q.z*q.z + q.w*q.w);
        float inv = 1.0f / fmaxf(n, 1e-8f);
        float qw = q.x*inv, qx = q.y*inv, qy = q.z*inv, qz = q.w*inv;
        float px = ctrl_pos[cp*3+0], py = ctrl_pos[cp*3+1], pz = ctrl_pos[cp*3+2];
        float tx = ctrl_trans[cp*3+0], ty = ctrl_trans[cp*3+1], tz = ctrl_trans[cp*3+2];
        float3 rp = quat_rotate(qw, qx, qy, qz, px, py, pz);
        sT[cp * 3 + 0] = make_float4(qw, qx, qy, qz);
        sT[cp * 3 + 1] = make_float4(n, px + tx - rp.x, py + ty - rp.y, pz + tz - rp.z);
    }
    __syncthreads();

    const long long gstride = (long long)gridDim.x * blockDim.x;

    for (long long i = (long long)blockIdx.x * blockDim.x + threadIdx.x;
         i < N; i += gstride) {

        // per-gaussian inputs (rows are 40B, 8B-aligned -> int2/float2)
        int   idx[KNB];
        float wt[KNB];
        {
            const int2*   ip = (const int2*)(indices + i * KNB);
            const float2* wp = (const float2*)(weights + i * KNB);
#pragma unroll
            for (int k = 0; k < KNB / 2; k++) {
                int2 iv = ip[k]; float2 wv = wp[k];
                idx[2 * k] = iv.x; idx[2 * k + 1] = iv.y;
                wt[2 * k] = wv.x;  wt[2 * k + 1] = wv.y;
            }
            if (KNB & 1) {
                idx[KNB - 1] = indices[i * KNB + KNB - 1];
                wt[KNB - 1]  = weights[i * KNB + KNB - 1];
            }
        }
        float mx = means[i * 3 + 0];
        float my = means[i * 3 + 1];
        float mz = means[i * 3 + 2];
        float4 g = ((const float4*)quats)[i];

        float dmx = 0.f, dmy = 0.f, dmz = 0.f;
        float qaw = 0.f, qax = 0.f, qay = 0.f, qaz = 0.f;

#pragma unroll
        for (int k = 0; k < KNB; k++) {
            int   cp = idx[k];
            float w  = wt[k];
            float4 qh = sT[cp * 3 + 0];   // qw qx qy qz (normalized)
            float4 nb = sT[cp * 3 + 1];   // |q| bx by bz
            float3 r  = quat_rotate(qh.x, qh.y, qh.z, qh.w, mx, my, mz);
            dmx = fmaf(w, r.x + nb.y, dmx);
            dmy = fmaf(w, r.y + nb.z, dmy);
            dmz = fmaf(w, r.z + nb.w, dmz);
            float wn = w * nb.x;
            qaw = fmaf(wn, qh.x, qaw);
            qax = fmaf(wn, qh.y, qax);
            qay = fmaf(wn, qh.z, qay);
            qaz = fmaf(wn, qh.w, qaz);
        }

        out_means[i * 3 + 0] = dmx;
        out_means[i * 3 + 1] = dmy;
        out_means[i * 3 + 2] = dmz;

        float n   = sqrtf(qaw*qaw + qax*qax + qay*qay + qaz*qaz);
        float inv = 1.0f / fmaxf(n, 1e-8f);
        float bw = qaw*inv, bx = qax*inv, by = qay*inv, bz = qaz*inv;
        float gw = g.x, gx = g.y, gy = g.z, gz = g.w;
        float ow = bw*gw - bx*gx - by*gy - bz*gz;
        float ox = bw*gx + bx*gw + by*gz - bz*gy;
        float oy = bw*gy - bx*gz + by*gw + bz*gx;
        float oz = bw*gz + bx*gy - by*gx + bz*gw;
        ((float4*)out_quats)[i] = make_float4(ow, ox, oy, oz);
    }
}

// generic fallback (runtime K_NB) — correctness path only
__global__ __launch_bounds__(256, 8) void deform_kernel_generic(
    const float* __restrict__ means,
    const float* __restrict__ quats,
    const float* __restrict__ weights,
    const float* __restrict__ ctrl_trans,
    const float* __restrict__ ctrl_rot,
    const float* __restrict__ ctrl_pos,
    const int*   __restrict__ indices,
    float* __restrict__ out_means,
    float* __restrict__ out_quats,
    int N, int K_NB, int K_TOTAL)
{
    extern __shared__ float4 sT[];
    for (int cp = threadIdx.x; cp < K_TOTAL; cp += blockDim.x) {
        float4 q = ((const float4*)ctrl_rot)[cp];
        float n   = sqrtf(q.x*q.x + q.y*q.y + q.z*q.z + q.w*q.w);
        float inv = 1.0f / fmaxf(n, 1e-8f);
        float qw = q.x*inv, qx = q.y*inv, qy = q.z*inv, qz = q.w*inv;
        float px = ctrl_pos[cp*3+0], py = ctrl_pos[cp*3+1], pz = ctrl_pos[cp*3+2];
        float tx = ctrl_trans[cp*3+0], ty = ctrl_trans[cp*3+1], tz = ctrl_trans[cp*3+2];
        float3 rp = quat_rotate(qw, qx, qy, qz, px, py, pz);
        sT[cp * 3 + 0] = make_float4(qw, qx, qy, qz);
        sT[cp * 3 + 1] = make_float4(n, px + tx - rp.x, py + ty - rp.y, pz + tz - rp.z);
    }
    __syncthreads();

    long long i = (long long)blockIdx.x * blockDim.x + threadIdx.x;
    if (i >= N) return;

    float mx = means[i*3+0], my = means[i*3+1], mz = means[i*3+2];
    float dmx = 0.f, dmy = 0.f, dmz = 0.f;
    float qaw = 0.f, qax = 0.f, qay = 0.f, qaz = 0.f;
    for (int k = 0; k < K_NB; k++) {
        int   cp = indices[i * K_NB + k];
        float w  = weights[i * K_NB + k];
        float4 qh = sT[cp * 3 + 0];
        float4 nb = sT[cp * 3 + 1];
        float3 r  = quat_rotate(qh.x, qh.y, qh.z, qh.w, mx, my, mz);
        dmx = fmaf(w, r.x + nb.y, dmx);
        dmy = fmaf(w, r.y + nb.z, dmy);
        dmz = fmaf(w, r.z + nb.w, dmz);
        float wn = w * nb.x;
        qaw = fmaf(wn, qh.x, qaw); qax = fmaf(wn, qh.y, qax);
        qay = fmaf(wn, qh.z, qay); qaz = fmaf(wn, qh.w, qaz);
    }
    out_means[i*3+0] = dmx; out_means[i*3+1] = dmy; out_means[i*3+2] = dmz;
    float n   = sqrtf(qaw*qaw + qax*qax + qay*qay + qaz*qaz);
    float inv = 1.0f / fmaxf(n, 1e-8f);
    float bw = qaw*inv, bx = qax*inv, by = qay*inv, bz = qaz*inv;
    float4 gq = ((const float4*)quats)[i];
    float gw = gq.x, gx = gq.y, gy = gq.z, gz = gq.w;
    ((float4*)out_quats)[i] = make_float4(
        bw*gw - bx*gx - by*gy - bz*gz,
        bw*gx + bx*gw + by*gz - bz*gy,
        bw*gy - bx*gz + by*gw + bz*gx,
        bw*gz + bx*gy - by*gx + bz*gw);
}

extern "C" void kernel_launch(void* const* d_in, const int* in_sizes, int n_in,
                              void* d_out, int out_size, void* d_ws, size_t ws_size,
                              hipStream_t stream) {
    const float* means      = (const float*)d_in[0];
    const float* quats      = (const float*)d_in[1];
    const float* weights    = (const float*)d_in[2];
    const float* ctrl_trans = (const float*)d_in[3];
    const float* ctrl_rot   = (const float*)d_in[4];
    const float* ctrl_pos   = (const float*)d_in[5];
    const int*   indices    = (const int*)d_in[6];

    int N       = in_sizes[0] / 3;
    int K_NB    = in_sizes[2] / N;
    int K_TOTAL = in_sizes[3] / 3;

    float* out_means = (float*)d_out;
    float* out_quats = (float*)d_out + (long long)N * 3;

    const int block = 256;
    size_t smem = (size_t)K_TOTAL * 3 * sizeof(float4);

    int needed = (int)((N + (long long)block - 1) / block);
    int grid = 2048;                 // 8 blocks/CU co-resident; ~2 chunks each
    if (needed < grid) grid = needed;

    switch (K_NB) {
    case 4:  deform_kernel<4 ><<<grid, block, smem, stream>>>(means, quats, weights, ctrl_trans, ctrl_rot, ctrl_pos, indices, out_means, out_quats, N, K_TOTAL); break;
    case 6:  deform_kernel<6 ><<<grid, block, smem, stream>>>(means, quats, weights, ctrl_trans, ctrl_rot, ctrl_pos, indices, out_means, out_quats, N, K_TOTAL); break;
    case 8:  deform_kernel<8 ><<<grid, block, smem, stream>>>(means, quats, weights, ctrl_trans, ctrl_rot, ctrl_pos, indices, out_means, out_quats, N, K_TOTAL); break;
    case 10: deform_kernel<10><<<grid, block, smem, stream>>>(means, quats, weights, ctrl_trans, ctrl_rot, ctrl_pos, indices, out_means, out_quats, N, K_TOTAL); break;
    case 12: deform_kernel<12><<<grid, block, smem, stream>>>(means, quats, weights, ctrl_trans, ctrl_rot, ctrl_pos, indices, out_means, out_quats, N, K_TOTAL); break;
    case 16: deform_kernel<16><<<grid, block, smem, stream>>>(means, quats, weights, ctrl_trans, ctrl_rot, ctrl_pos, indices, out_means, out_quats, N, K_TOTAL); break;
    default: {
        int g2 = needed;
        deform_kernel_generic<<<g2, block, smem, stream>>>(
            means, quats, weights, ctrl_trans, ctrl_rot, ctrl_pos, indices,
            out_means, out_quats, N, K_NB, K_TOTAL);
        break;
    }
    }
}

// Round 5
// 147.716 us; speedup vs baseline: 2.7152x; 2.7152x over previous
//
#include <hip/hip_runtime.h>
#include <math.h>

// Deformation4D: N=1M gaussians, K_NB=10, K_TOTAL=300 control points.
// R5 = R1's spill-free skeleton (one gaussian/thread, fully-unrolled loop,
// loads issued directly in the loop body, NO per-thread arrays, NO min-wave
// launch bound -- R2/R3/R4 showed min-occupancy bounds force scratch spill:
// WRITE_SIZE 27->35->243->617 MB) + compressed LDS record:
//   sT[cp*3+0] = qhat(w,x,y,z)   sT[cp*3+1] = (|q|, bx, by, bz)
//   b = p + t - rot(qhat, p)
// 2 ds_read_b128 per neighbor (was 4); rotation done in registers:
//   dm   = sum_k w_k * (rot(qhat_k, m) + b_k)
//   qacc = sum_k (w_k * |q|_k) * qhat_k   (== sum w_k * q_raw_k)
// Stride 3 float4s = 12 dwords -> cp*12 mod 32 spans all 8 4-bank groups.

__device__ __forceinline__ float3 quat_rotate(float qw, float qx, float qy, float qz,
                                              float vx, float vy, float vz) {
    // v' = v + qw*t + cross(qv, t),  t = 2*cross(qv, v)
    float cx = qy * vz - qz * vy;
    float cy = qz * vx - qx * vz;
    float cz = qx * vy - qy * vx;
    float tx = cx + cx, ty = cy + cy, tz = cz + cz;
    float rx = fmaf(qy, tz, fmaf(-qz, ty, fmaf(qw, tx, vx)));
    float ry = fmaf(qz, tx, fmaf(-qx, tz, fmaf(qw, ty, vy)));
    float rz = fmaf(qx, ty, fmaf(-qy, tx, fmaf(qw, tz, vz)));
    return make_float3(rx, ry, rz);
}

template <int KNB>
__global__ __launch_bounds__(256) void deform_kernel(
    const float* __restrict__ means,
    const float* __restrict__ quats,
    const float* __restrict__ weights,
    const float* __restrict__ ctrl_trans,
    const float* __restrict__ ctrl_rot,
    const float* __restrict__ ctrl_pos,
    const int*   __restrict__ indices,
    float* __restrict__ out_means,
    float* __restrict__ out_quats,
    int N, int K_TOTAL)
{
    extern __shared__ float4 sT[];   // sT[cp*3+0]=qhat, sT[cp*3+1]=(|q|,b)

    // ---- build compressed control-point table ----
    for (int cp = threadIdx.x; cp < K_TOTAL; cp += blockDim.x) {
        float4 q = ((const float4*)ctrl_rot)[cp];
        float n   = sqrtf(q.x*q.x + q.y*q.y + q.z*q.z + q.w*q.w);
        float inv = 1.0f / fmaxf(n, 1e-8f);
        float qw = q.x*inv, qx = q.y*inv, qy = q.z*inv, qz = q.w*inv;
        float px = ctrl_pos[cp*3+0], py = ctrl_pos[cp*3+1], pz = ctrl_pos[cp*3+2];
        float tx = ctrl_trans[cp*3+0], ty = ctrl_trans[cp*3+1], tz = ctrl_trans[cp*3+2];
        float3 rp = quat_rotate(qw, qx, qy, qz, px, py, pz);
        sT[cp * 3 + 0] = make_float4(qw, qx, qy, qz);
        sT[cp * 3 + 1] = make_float4(n, px + tx - rp.x, py + ty - rp.y, pz + tz - rp.z);
    }
    __syncthreads();

    const int i = blockIdx.x * blockDim.x + threadIdx.x;
    if (i >= N) return;

    const int2*   ip = (const int2*)(indices + (long long)i * KNB);
    const float2* wp = (const float2*)(weights + (long long)i * KNB);

    const float mx = means[i * 3 + 0];
    const float my = means[i * 3 + 1];
    const float mz = means[i * 3 + 2];

    float dmx = 0.f, dmy = 0.f, dmz = 0.f;
    float qaw = 0.f, qax = 0.f, qay = 0.f, qaz = 0.f;

#pragma unroll
    for (int kk = 0; kk < KNB / 2; kk++) {
        int2   iv = ip[kk];
        float2 wv = wp[kk];
#pragma unroll
        for (int h = 0; h < 2; h++) {
            int   cp = (h == 0) ? iv.x : iv.y;
            float w  = (h == 0) ? wv.x : wv.y;
            float4 qh = sT[cp * 3 + 0];   // qw qx qy qz (normalized)
            float4 nb = sT[cp * 3 + 1];   // |q| bx by bz
            float3 r  = quat_rotate(qh.x, qh.y, qh.z, qh.w, mx, my, mz);
            dmx = fmaf(w, r.x + nb.y, dmx);
            dmy = fmaf(w, r.y + nb.z, dmy);
            dmz = fmaf(w, r.z + nb.w, dmz);
            float wn = w * nb.x;
            qaw = fmaf(wn, qh.x, qaw);
            qax = fmaf(wn, qh.y, qax);
            qay = fmaf(wn, qh.z, qay);
            qaz = fmaf(wn, qh.w, qaz);
        }
    }
    if (KNB & 1) {
        int   cp = indices[(long long)i * KNB + KNB - 1];
        float w  = weights[(long long)i * KNB + KNB - 1];
        float4 qh = sT[cp * 3 + 0];
        float4 nb = sT[cp * 3 + 1];
        float3 r  = quat_rotate(qh.x, qh.y, qh.z, qh.w, mx, my, mz);
        dmx = fmaf(w, r.x + nb.y, dmx);
        dmy = fmaf(w, r.y + nb.z, dmy);
        dmz = fmaf(w, r.z + nb.w, dmz);
        float wn = w * nb.x;
        qaw = fmaf(wn, qh.x, qaw); qax = fmaf(wn, qh.y, qax);
        qay = fmaf(wn, qh.z, qay); qaz = fmaf(wn, qh.w, qaz);
    }

    out_means[i * 3 + 0] = dmx;
    out_means[i * 3 + 1] = dmy;
    out_means[i * 3 + 2] = dmz;

    // normalize blended quaternion, then Hamilton product with gaussian quat
    float n   = sqrtf(qaw*qaw + qax*qax + qay*qay + qaz*qaz);
    float inv = 1.0f / fmaxf(n, 1e-8f);
    float bw = qaw*inv, bx = qax*inv, by = qay*inv, bz = qaz*inv;

    float4 g = ((const float4*)quats)[i];
    float gw = g.x, gx = g.y, gy = g.z, gz = g.w;
    float ow = bw*gw - bx*gx - by*gy - bz*gz;
    float ox = bw*gx + bx*gw + by*gz - bz*gy;
    float oy = bw*gy - bx*gz + by*gw + bz*gx;
    float oz = bw*gz + bx*gy - by*gx + bz*gw;
    ((float4*)out_quats)[i] = make_float4(ow, ox, oy, oz);
}

// generic fallback (runtime K_NB) — correctness path only
__global__ __launch_bounds__(256) void deform_kernel_generic(
    const float* __restrict__ means,
    const float* __restrict__ quats,
    const float* __restrict__ weights,
    const float* __restrict__ ctrl_trans,
    const float* __restrict__ ctrl_rot,
    const float* __restrict__ ctrl_pos,
    const int*   __restrict__ indices,
    float* __restrict__ out_means,
    float* __restrict__ out_quats,
    int N, int K_NB, int K_TOTAL)
{
    extern __shared__ float4 sT[];
    for (int cp = threadIdx.x; cp < K_TOTAL; cp += blockDim.x) {
        float4 q = ((const float4*)ctrl_rot)[cp];
        float n   = sqrtf(q.x*q.x + q.y*q.y + q.z*q.z + q.w*q.w);
        float inv = 1.0f / fmaxf(n, 1e-8f);
        float qw = q.x*inv, qx = q.y*inv, qy = q.z*inv, qz = q.w*inv;
        float px = ctrl_pos[cp*3+0], py = ctrl_pos[cp*3+1], pz = ctrl_pos[cp*3+2];
        float tx = ctrl_trans[cp*3+0], ty = ctrl_trans[cp*3+1], tz = ctrl_trans[cp*3+2];
        float3 rp = quat_rotate(qw, qx, qy, qz, px, py, pz);
        sT[cp * 3 + 0] = make_float4(qw, qx, qy, qz);
        sT[cp * 3 + 1] = make_float4(n, px + tx - rp.x, py + ty - rp.y, pz + tz - rp.z);
    }
    __syncthreads();

    long long i = (long long)blockIdx.x * blockDim.x + threadIdx.x;
    if (i >= N) return;

    float mx = means[i*3+0], my = means[i*3+1], mz = means[i*3+2];
    float dmx = 0.f, dmy = 0.f, dmz = 0.f;
    float qaw = 0.f, qax = 0.f, qay = 0.f, qaz = 0.f;
    for (int k = 0; k < K_NB; k++) {
        int   cp = indices[i * K_NB + k];
        float w  = weights[i * K_NB + k];
        float4 qh = sT[cp * 3 + 0];
        float4 nb = sT[cp * 3 + 1];
        float3 r  = quat_rotate(qh.x, qh.y, qh.z, qh.w, mx, my, mz);
        dmx = fmaf(w, r.x + nb.y, dmx);
        dmy = fmaf(w, r.y + nb.z, dmy);
        dmz = fmaf(w, r.z + nb.w, dmz);
        float wn = w * nb.x;
        qaw = fmaf(wn, qh.x, qaw); qax = fmaf(wn, qh.y, qax);
        qay = fmaf(wn, qh.z, qay); qaz = fmaf(wn, qh.w, qaz);
    }
    out_means[i*3+0] = dmx; out_means[i*3+1] = dmy; out_means[i*3+2] = dmz;
    float n   = sqrtf(qaw*qaw + qax*qax + qay*qay + qaz*qaz);
    float inv = 1.0f / fmaxf(n, 1e-8f);
    float bw = qaw*inv, bx = qax*inv, by = qay*inv, bz = qaz*inv;
    float4 gq = ((const float4*)quats)[i];
    float gw = gq.x, gx = gq.y, gy = gq.z, gz = gq.w;
    ((float4*)out_quats)[i] = make_float4(
        bw*gw - bx*gx - by*gy - bz*gz,
        bw*gx + bx*gw + by*gz - bz*gy,
        bw*gy - bx*gz + by*gw + bz*gx,
        bw*gz + bx*gy - by*gx + bz*gw);
}

extern "C" void kernel_launch(void* const* d_in, const int* in_sizes, int n_in,
                              void* d_out, int out_size, void* d_ws, size_t ws_size,
                              hipStream_t stream) {
    const float* means      = (const float*)d_in[0];
    const float* quats      = (const float*)d_in[1];
    const float* weights    = (const float*)d_in[2];
    const float* ctrl_trans = (const float*)d_in[3];
    const float* ctrl_rot   = (const float*)d_in[4];
    const float* ctrl_pos   = (const float*)d_in[5];
    const int*   indices    = (const int*)d_in[6];

    int N       = in_sizes[0] / 3;
    int K_NB    = in_sizes[2] / N;
    int K_TOTAL = in_sizes[3] / 3;

    float* out_means = (float*)d_out;
    float* out_quats = (float*)d_out + (long long)N * 3;

    const int block = 256;
    int grid = (int)((N + (long long)block - 1) / block);
    size_t smem = (size_t)K_TOTAL * 3 * sizeof(float4);

    switch (K_NB) {
    case 4:  deform_kernel<4 ><<<grid, block, smem, stream>>>(means, quats, weights, ctrl_trans, ctrl_rot, ctrl_pos, indices, out_means, out_quats, N, K_TOTAL); break;
    case 6:  deform_kernel<6 ><<<grid, block, smem, stream>>>(means, quats, weights, ctrl_trans, ctrl_rot, ctrl_pos, indices, out_means, out_quats, N, K_TOTAL); break;
    case 8:  deform_kernel<8 ><<<grid, block, smem, stream>>>(means, quats, weights, ctrl_trans, ctrl_rot, ctrl_pos, indices, out_means, out_quats, N, K_TOTAL); break;
    case 10: deform_kernel<10><<<grid, block, smem, stream>>>(means, quats, weights, ctrl_trans, ctrl_rot, ctrl_pos, indices, out_means, out_quats, N, K_TOTAL); break;
    case 12: deform_kernel<12><<<grid, block, smem, stream>>>(means, quats, weights, ctrl_trans, ctrl_rot, ctrl_pos, indices, out_means, out_quats, N, K_TOTAL); break;
    case 16: deform_kernel<16><<<grid, block, smem, stream>>>(means, quats, weights, ctrl_trans, ctrl_rot, ctrl_pos, indices, out_means, out_quats, N, K_TOTAL); break;
    default:
        deform_kernel_generic<<<grid, block, smem, stream>>>(
            means, quats, weights, ctrl_trans, ctrl_rot, ctrl_pos, indices,
            out_means, out_quats, N, K_NB, K_TOTAL);
        break;
    }
}